// Round 6
// baseline (100.995 us; speedup 1.0000x reference)
//
#include <hip/hip_runtime.h>
#include <hip/hip_bf16.h>
#include <math.h>

#define B_N 4096
#define D_N 1024
#define K_N 256
#define TM 64        // rows per block tile
#define BK 16        // k per LDS tile
#define SPLITS 16
#define KCHUNK 64    // D_N / SPLITS
#define NT (KCHUNK / BK)   // 4 k-tiles per block

static constexpr float K_EPS = 1e-8f;

// ---------------------------------------------------------------------------
// Kernel 1: normalize centroids into ws as TRANSPOSED cnT[D][K]; compute
// datapoint inverse norms. grid = K_N + B_N blocks, 256 threads.
// ---------------------------------------------------------------------------
__global__ __launch_bounds__(256) void knorm_kernel(
    const float* __restrict__ dp, const float* __restrict__ cent,
    float* __restrict__ cnT, float* __restrict__ invn)
{
    int bid = blockIdx.x;
    int tid = threadIdx.x;
    bool isC = bid < K_N;
    int row = isC ? bid : bid - K_N;
    const float* src = isC ? (cent + (size_t)row * D_N) : (dp + (size_t)row * D_N);
    float4 v = reinterpret_cast<const float4*>(src)[tid];   // D/4 == 256 == blockDim
    float s = v.x * v.x + v.y * v.y + v.z * v.z + v.w * v.w;
    #pragma unroll
    for (int o = 32; o > 0; o >>= 1) s += __shfl_down(s, o);
    __shared__ float red[4];
    __shared__ float s_inv;
    if ((tid & 63) == 0) red[tid >> 6] = s;
    __syncthreads();
    if (tid == 0) {
        float t = red[0] + red[1] + red[2] + red[3];
        s_inv = 1.0f / fmaxf(sqrtf(t), K_EPS);
    }
    __syncthreads();
    float inv = s_inv;
    if (isC) {
        // transposed scatter: cnT[d][k] = cn[k][d]; 1 MB total, L2 merges lines
        cnT[(size_t)(tid * 4 + 0) * K_N + row] = v.x * inv;
        cnT[(size_t)(tid * 4 + 1) * K_N + row] = v.y * inv;
        cnT[(size_t)(tid * 4 + 2) * K_N + row] = v.z * inv;
        cnT[(size_t)(tid * 4 + 3) * K_N + row] = v.w * inv;
    } else if (tid == 0) {
        invn[row] = inv;
    }
}

// ---------------------------------------------------------------------------
// Kernel 2: split-K GEMM partials. Classic LDS-tiled f32 GEMM:
//   block tile 64x256, 8x8 register tile/thread, BK=16, double-buffered LDS.
//   No scalar loads, no per-element global loads in the inner loop.
//   A staged per-lane float4 -> ds_write (issue-early/write-late);
//   B staged via linear global_load_lds width-16.
// grid = 64 row-tiles x 16 k-splits = 1024 blocks, 256 threads (4 waves);
// 4 blocks/CU (LDS 40KB). Partials -> dp_cluster region (64MB, exact fit).
// ---------------------------------------------------------------------------
__global__ __launch_bounds__(256) void kgemm_kernel(
    const float* __restrict__ dp, const float* __restrict__ cnT,
    float* __restrict__ part)
{
    __shared__ float As[2][BK][TM];    // 2 x 4 KB, [k][m]
    __shared__ float Bs[2][BK][K_N];   // 2 x 16 KB, [k][n]
    int tid = threadIdx.x;
    int bx  = blockIdx.x;
    int mt  = bx & 63;        // row tile
    int s   = bx >> 6;        // k-split 0..15
    int brow  = mt * TM;
    int kbase = s * KCHUNK;

    int ty = tid >> 5;        // 0..7: rows {h*32 + ty*4 + i}
    int tx = tid & 31;        // 0..31: cols {g*128 + tx*4 + j}
    int arow = tid & 63;      // A staging: row within tile
    int akq  = tid >> 6;      // A staging: k-quad 0..3

    // B tile stage: 16 KB linear, 4 x global_load_lds(16B) per thread.
    auto stageB = [&](int buf, int koff) {
        const char* src = (const char*)(cnT + (size_t)(kbase + koff) * K_N);
        char* dst = (char*)&Bs[buf][0][0];
        #pragma unroll
        for (int q = 0; q < 4; ++q) {
            unsigned off = (unsigned)q * 4096u + (unsigned)tid * 16u;
            __builtin_amdgcn_global_load_lds(
                (const __attribute__((address_space(1))) unsigned*)(src + off),
                (__attribute__((address_space(3))) unsigned*)(dst + off),
                16, 0, 0);
        }
    };
    // A: each thread loads one row's 4 consecutive k as float4 (16 k x 64 rows)
    auto loadA = [&](int koff) {
        return *reinterpret_cast<const float4*>(
            &dp[(size_t)(brow + arow) * D_N + kbase + koff + akq * 4]);
    };
    auto writeA = [&](int buf, float4 a) {
        As[buf][akq * 4 + 0][arow] = a.x;   // 256B contiguous per wave: no conflict
        As[buf][akq * 4 + 1][arow] = a.y;
        As[buf][akq * 4 + 2][arow] = a.z;
        As[buf][akq * 4 + 3][arow] = a.w;
    };

    float acc[2][4][2][4] = {};   // [row-half][i][col-half][j]

    // prologue: fill buffer 0
    float4 a0 = loadA(0);
    stageB(0, 0);
    writeA(0, a0);
    __syncthreads();

    int cur = 0;
    #pragma unroll 1
    for (int t = 0; t < NT; ++t) {
        float4 an;
        if (t + 1 < NT) {                    // issue-early (T14)
            an = loadA((t + 1) * BK);
            stageB(cur ^ 1, (t + 1) * BK);
        }
        #pragma unroll
        for (int kk = 0; kk < BK; ++kk) {
            float4 aL = *reinterpret_cast<const float4*>(&As[cur][kk][ty * 4]);
            float4 aH = *reinterpret_cast<const float4*>(&As[cur][kk][32 + ty * 4]);
            float4 bL = *reinterpret_cast<const float4*>(&Bs[cur][kk][tx * 4]);
            float4 bH = *reinterpret_cast<const float4*>(&Bs[cur][kk][128 + tx * 4]);
            float ar[2][4] = {{aL.x, aL.y, aL.z, aL.w}, {aH.x, aH.y, aH.z, aH.w}};
            float bc[2][4] = {{bL.x, bL.y, bL.z, bL.w}, {bH.x, bH.y, bH.z, bH.w}};
            #pragma unroll
            for (int h = 0; h < 2; ++h)
                #pragma unroll
                for (int i = 0; i < 4; ++i)
                    #pragma unroll
                    for (int g = 0; g < 2; ++g)
                        #pragma unroll
                        for (int j = 0; j < 4; ++j)
                            acc[h][i][g][j] += ar[h][i] * bc[g][j];
        }
        if (t + 1 < NT) writeA(cur ^ 1, an);   // write-late
        __syncthreads();
        cur ^= 1;
    }

    float* pout = part + (size_t)s * (B_N * K_N);
    #pragma unroll
    for (int h = 0; h < 2; ++h)
        #pragma unroll
        for (int i = 0; i < 4; ++i) {
            int r = brow + h * 32 + ty * 4 + i;
            #pragma unroll
            for (int g = 0; g < 2; ++g) {
                float4 o4 = make_float4(acc[h][i][g][0], acc[h][i][g][1],
                                        acc[h][i][g][2], acc[h][i][g][3]);
                *reinterpret_cast<float4*>(
                    &pout[(size_t)r * K_N + g * 128 + tx * 4]) = o4;
            }
        }
}

// ---------------------------------------------------------------------------
// Kernel 2b: sum the 16 partials, scale by invn, write sims, per-row top-2.
// grid = 1024 blocks x 256 threads; wave per row.
// ---------------------------------------------------------------------------
__global__ __launch_bounds__(256) void kreduce_kernel(
    const float* __restrict__ part, const float* __restrict__ invn,
    float* __restrict__ out_sims, float* __restrict__ out_dpidx,
    float* __restrict__ out_hnidx, float* __restrict__ out_top1,
    int* __restrict__ ws_dpidx, int* __restrict__ ws_hnidx)
{
    int tid = threadIdx.x;
    int lc  = tid & 63;
    int row = blockIdx.x * 4 + (tid >> 6);

    const float4* p = reinterpret_cast<const float4*>(part);
    size_t off = (size_t)row * (K_N / 4) + lc;
    const size_t stride = (size_t)B_N * (K_N / 4);
    float c0 = 0.f, c1 = 0.f, c2 = 0.f, c3 = 0.f;
    #pragma unroll
    for (int s = 0; s < SPLITS; ++s) {
        float4 v = p[off + (size_t)s * stride];
        c0 += v.x; c1 += v.y; c2 += v.z; c3 += v.w;
    }
    float iv = invn[row];
    c0 *= iv; c1 *= iv; c2 *= iv; c3 *= iv;

    reinterpret_cast<float4*>(out_sims)[off] = make_float4(c0, c1, c2, c3);

    // per-row top-2 across the wave (ties -> lower index, matching jnp)
    float v1b = c0; int i1 = lc * 4;
    float v2b = -INFINITY; int i2 = 0;
    {
        float vals[3] = {c1, c2, c3};
        #pragma unroll
        for (int j = 0; j < 3; ++j) {
            float val = vals[j]; int idx = lc * 4 + j + 1;
            if (val > v1b) { v2b = v1b; i2 = i1; v1b = val; i1 = idx; }
            else if (val > v2b) { v2b = val; i2 = idx; }
        }
    }
    #pragma unroll
    for (int o = 1; o < 64; o <<= 1) {
        float ov1 = __shfl_xor(v1b, o);
        float ov2 = __shfl_xor(v2b, o);
        int   oi1 = __shfl_xor(i1, o);
        int   oi2 = __shfl_xor(i2, o);
        if (ov1 > v1b || (ov1 == v1b && oi1 < i1)) {
            float nv2; int ni2;
            if (v1b > ov2 || (v1b == ov2 && i1 < oi2)) { nv2 = v1b; ni2 = i1; }
            else { nv2 = ov2; ni2 = oi2; }
            v1b = ov1; i1 = oi1; v2b = nv2; i2 = ni2;
        } else if (ov1 > v2b || (ov1 == v2b && oi1 < i2)) {
            v2b = ov1; i2 = oi1;
        }
    }
    if (lc == 0) {
        out_dpidx[row] = (float)i1;
        out_hnidx[row] = (float)i2;
        out_top1[row]  = v2b;
        ws_dpidx[row]  = i1;
        ws_hnidx[row]  = i2;
    }
}

// ---------------------------------------------------------------------------
// Kernel 3: all remaining outputs. grid = 2*B + K blocks:
//   [0, B)      : gather dp_centroid + hard_negative rows (float4/thread each)
//   [B, 2B)     : dp_cluster row i (16 floats/thread, int4 index loads)
//   [2B, 2B+K)  : index_dp row k (16 floats/thread)
// ---------------------------------------------------------------------------
__global__ __launch_bounds__(256) void kout_kernel(
    const float* __restrict__ cent,
    const int* __restrict__ dpidx, const int* __restrict__ hnidx,
    float* __restrict__ out_dpcent, float* __restrict__ out_hneg,
    float* __restrict__ out_cluster, float* __restrict__ out_indexdp)
{
    int bid = blockIdx.x;
    int tid = threadIdx.x;
    const int4* dpi4 = reinterpret_cast<const int4*>(dpidx);
    if (bid < B_N) {
        int b = bid;
        int i1 = dpidx[b], i2 = hnidx[b];
        float4 v1 = reinterpret_cast<const float4*>(cent + (size_t)i1 * D_N)[tid];
        float4 v2 = reinterpret_cast<const float4*>(cent + (size_t)i2 * D_N)[tid];
        reinterpret_cast<float4*>(out_dpcent + (size_t)b * D_N)[tid] = v1;
        reinterpret_cast<float4*>(out_hneg   + (size_t)b * D_N)[tid] = v2;
    } else if (bid < 2 * B_N) {
        int i = bid - B_N;
        int me = dpidx[i];
        float* dst = out_cluster + (size_t)i * B_N;
        #pragma unroll
        for (int q = 0; q < 4; ++q) {
            int j = tid * 16 + q * 4;
            int4 ix = dpi4[j >> 2];
            float4 v;
            v.x = (ix.x == me && (j + 0) != i) ? 1.0f : 0.0f;
            v.y = (ix.y == me && (j + 1) != i) ? 1.0f : 0.0f;
            v.z = (ix.z == me && (j + 2) != i) ? 1.0f : 0.0f;
            v.w = (ix.w == me && (j + 3) != i) ? 1.0f : 0.0f;
            *reinterpret_cast<float4*>(dst + j) = v;
        }
    } else {
        int k = bid - 2 * B_N;
        float* dst = out_indexdp + (size_t)k * B_N;
        #pragma unroll
        for (int q = 0; q < 4; ++q) {
            int j = tid * 16 + q * 4;
            int4 ix = dpi4[j >> 2];
            float4 v;
            v.x = (ix.x == k) ? 1.0f : 0.0f;
            v.y = (ix.y == k) ? 1.0f : 0.0f;
            v.z = (ix.z == k) ? 1.0f : 0.0f;
            v.w = (ix.w == k) ? 1.0f : 0.0f;
            *reinterpret_cast<float4*>(dst + j) = v;
        }
    }
}

extern "C" void kernel_launch(void* const* d_in, const int* in_sizes, int n_in,
                              void* d_out, int out_size, void* d_ws, size_t ws_size,
                              hipStream_t stream)
{
    const float* dp   = (const float*)d_in[0];   // 4096 x 1024 f32
    const float* cent = (const float*)d_in[1];   // 256 x 1024 f32
    // d_in[2] (batch_cos_sim) is unused by the reference outputs.
    float* out = (float*)d_out;

    // output layout (element offsets, all read back as f32)
    float* o_sims   = out;                 // 4096*256
    float* o_dpidx  = out + 1048576;       // 4096
    float* o_clust  = out + 1052672;       // 4096*4096  (also split-K scratch)
    float* o_idxdp  = out + 17829888;      // 256*4096
    float* o_dpcent = out + 18878464;      // 4096*1024
    float* o_hneg   = out + 23072768;      // 4096*1024
    float* o_hnidx  = out + 27267072;      // 4096
    float* o_top1   = out + 27271168;      // 4096

    char* ws = (char*)d_ws;
    float* cnT  = (float*)ws;                         // 1 MiB transposed centroids
    int*   widx = (int*)(ws + (1 << 20));             // 16 KiB
    int*   whn  = (int*)(ws + (1 << 20) + 16384);     // 16 KiB
    float* winv = (float*)(ws + (1 << 20) + 32768);   // 16 KiB

    float* part = o_clust;   // 16 x 4MB split-K partials = 64MB, exact fit,
                             // overwritten later by kout

    hipLaunchKernelGGL(knorm_kernel, dim3(K_N + B_N), dim3(256), 0, stream,
                       dp, cent, cnT, winv);
    hipLaunchKernelGGL(kgemm_kernel, dim3(64 * SPLITS), dim3(256), 0, stream,
                       dp, cnT, part);
    hipLaunchKernelGGL(kreduce_kernel, dim3(B_N / 4), dim3(256), 0, stream,
                       part, winv, o_sims, o_dpidx, o_hnidx, o_top1, widx, whn);
    hipLaunchKernelGGL(kout_kernel, dim3(2 * B_N + K_N), dim3(256), 0, stream,
                       cent, widx, whn, o_dpcent, o_hneg, o_clust, o_idxdp);
}

// Round 7
// 89.842 us; speedup vs baseline: 1.1242x; 1.1242x over previous
//
#include <hip/hip_runtime.h>
#include <hip/hip_bf16.h>
#include <math.h>

#define B_N 4096
#define D_N 1024
#define K_N 256

typedef __attribute__((ext_vector_type(8))) short bf16x8;   // 4 VGPR
typedef __attribute__((ext_vector_type(4))) float f32x4;    // MFMA C/D

static constexpr float K_EPS = 1e-8f;

static __device__ __forceinline__ unsigned short f32_to_bf16_rne(float f) {
    unsigned x = __builtin_bit_cast(unsigned, f);
    unsigned r = (x + 0x7FFFu + ((x >> 16) & 1u)) >> 16;
    return (unsigned short)r;
}
static __device__ __forceinline__ float bf16_bits_to_f32(unsigned short h) {
    unsigned x = ((unsigned)h) << 16;
    return __builtin_bit_cast(float, x);
}

// ---------------------------------------------------------------------------
// Kernel 1: normalize rows; emit bf16 hi/lo split of normalized vectors.
// dn = dp/||dp||  -> dhi,dlo ; cn = cent/||cent|| -> chi,clo.
// grid = K_N + B_N blocks, 256 threads (1 row each, 4 f32 per thread).
// ---------------------------------------------------------------------------
__global__ __launch_bounds__(256) void knorm_kernel(
    const float* __restrict__ dp, const float* __restrict__ cent,
    ushort* __restrict__ dhi, ushort* __restrict__ dlo,
    ushort* __restrict__ chi, ushort* __restrict__ clo)
{
    int bid = blockIdx.x;
    int tid = threadIdx.x;
    bool isC = bid < K_N;
    int row = isC ? bid : bid - K_N;
    const float* src = isC ? (cent + (size_t)row * D_N) : (dp + (size_t)row * D_N);
    float4 v = reinterpret_cast<const float4*>(src)[tid];   // D/4 == 256 == blockDim
    float s = v.x * v.x + v.y * v.y + v.z * v.z + v.w * v.w;
    #pragma unroll
    for (int o = 32; o > 0; o >>= 1) s += __shfl_down(s, o);
    __shared__ float red[4];
    __shared__ float s_inv;
    if ((tid & 63) == 0) red[tid >> 6] = s;
    __syncthreads();
    if (tid == 0) {
        float t = red[0] + red[1] + red[2] + red[3];
        s_inv = 1.0f / fmaxf(sqrtf(t), K_EPS);
    }
    __syncthreads();
    float inv = s_inv;
    float e[4] = {v.x * inv, v.y * inv, v.z * inv, v.w * inv};
    ushort h4[4], l4[4];
    #pragma unroll
    for (int j = 0; j < 4; ++j) {
        ushort h = f32_to_bf16_rne(e[j]);
        float lo = e[j] - bf16_bits_to_f32(h);
        h4[j] = h;
        l4[j] = f32_to_bf16_rne(lo);
    }
    ushort* ph = (isC ? chi : dhi) + (size_t)row * D_N + tid * 4;
    ushort* pl = (isC ? clo : dlo) + (size_t)row * D_N + tid * 4;
    *reinterpret_cast<ushort4*>(ph) = make_ushort4(h4[0], h4[1], h4[2], h4[3]);
    *reinterpret_cast<ushort4*>(pl) = make_ushort4(l4[0], l4[1], l4[2], l4[3]);
}

// ---------------------------------------------------------------------------
// Kernel 2: sims = dn . cn^T via bf16 split-MFMA (3 products, err ~1e-7).
// grid = 256 blocks (1/CU), 256 threads (4 waves). Block tile 16 x 256;
// wave owns n-strip of 64 (4 MFMA n-tiles). A-tile (16 x 1024, hi+lo = 64KB)
// staged ONCE to LDS via linear global_load_lds; then a barrier-free K-loop:
// 2 ds_read_b128 (A-frags) + 8 L2-resident B-frag loads + 12 MFMA per k-step.
// MFMA 16x16x32: A lane{row=l&15, k=(l>>4)*8+j}; B lane{col=l&15, same k};
// D lane{col=l&15, row=(l>>4)*4+reg}.
// ---------------------------------------------------------------------------
__global__ __launch_bounds__(256) void kgemm_kernel(
    const ushort* __restrict__ dhi, const ushort* __restrict__ dlo,
    const ushort* __restrict__ chi, const ushort* __restrict__ clo,
    float* __restrict__ out_sims)
{
    __shared__ ushort Ah[16 * 1024];   // 32 KB, mirrors global row-major layout
    __shared__ ushort Al[16 * 1024];   // 32 KB
    int tid  = threadIdx.x;
    int lane = tid & 63;
    int wid  = tid >> 6;
    int lr   = lane & 15;
    int lg   = lane >> 4;
    int brow = blockIdx.x * 16;

    // Stage A hi+lo: both sides are linear 32 KB copies (16 consecutive rows).
    {
        const char* s0 = (const char*)(dhi + (size_t)brow * D_N);
        const char* s1 = (const char*)(dlo + (size_t)brow * D_N);
        char* d0 = (char*)Ah;
        char* d1 = (char*)Al;
        #pragma unroll
        for (int q = 0; q < 8; ++q) {
            unsigned off = (unsigned)(q * 4 + wid) * 1024u + (unsigned)lane * 16u;
            __builtin_amdgcn_global_load_lds(
                (const __attribute__((address_space(1))) unsigned*)(s0 + off),
                (__attribute__((address_space(3))) unsigned*)(d0 + off), 16, 0, 0);
            __builtin_amdgcn_global_load_lds(
                (const __attribute__((address_space(1))) unsigned*)(s1 + off),
                (__attribute__((address_space(3))) unsigned*)(d1 + off), 16, 0, 0);
        }
    }
    __syncthreads();

    f32x4 acc[4] = {};

    for (int k0 = 0; k0 < D_N; k0 += 32) {
        bf16x8 ah = *reinterpret_cast<const bf16x8*>(&Ah[lr * D_N + k0 + lg * 8]);
        bf16x8 al = *reinterpret_cast<const bf16x8*>(&Al[lr * D_N + k0 + lg * 8]);
        #pragma unroll
        for (int t = 0; t < 4; ++t) {
            size_t nb = (size_t)(wid * 64 + t * 16 + lr) * D_N + k0 + lg * 8;
            bf16x8 bh = *reinterpret_cast<const bf16x8*>(&chi[nb]);
            bf16x8 bl = *reinterpret_cast<const bf16x8*>(&clo[nb]);
            acc[t] = __builtin_amdgcn_mfma_f32_16x16x32_bf16(ah, bh, acc[t], 0, 0, 0);
            acc[t] = __builtin_amdgcn_mfma_f32_16x16x32_bf16(ah, bl, acc[t], 0, 0, 0);
            acc[t] = __builtin_amdgcn_mfma_f32_16x16x32_bf16(al, bh, acc[t], 0, 0, 0);
        }
    }

    #pragma unroll
    for (int t = 0; t < 4; ++t)
        #pragma unroll
        for (int r = 0; r < 4; ++r)
            out_sims[(size_t)(brow + lg * 4 + r) * K_N + wid * 64 + t * 16 + lr] =
                acc[t][r];
}

// ---------------------------------------------------------------------------
// Kernel 2b: read sims, per-row top-2 (value + index) via butterfly merge.
// grid = 1024 blocks x 256 threads; wave per row.
// ---------------------------------------------------------------------------
__global__ __launch_bounds__(256) void kreduce_kernel(
    const float* __restrict__ sims,
    float* __restrict__ out_dpidx, float* __restrict__ out_hnidx,
    float* __restrict__ out_top1,
    int* __restrict__ ws_dpidx, int* __restrict__ ws_hnidx)
{
    int tid = threadIdx.x;
    int lc  = tid & 63;
    int row = blockIdx.x * 4 + (tid >> 6);

    float4 c = reinterpret_cast<const float4*>(sims)[(size_t)row * (K_N / 4) + lc];

    // per-row top-2 across the wave (ties -> lower index, matching jnp)
    float v1b = c.x; int i1 = lc * 4;
    float v2b = -INFINITY; int i2 = 0;
    {
        float vals[3] = {c.y, c.z, c.w};
        #pragma unroll
        for (int j = 0; j < 3; ++j) {
            float val = vals[j]; int idx = lc * 4 + j + 1;
            if (val > v1b) { v2b = v1b; i2 = i1; v1b = val; i1 = idx; }
            else if (val > v2b) { v2b = val; i2 = idx; }
        }
    }
    #pragma unroll
    for (int o = 1; o < 64; o <<= 1) {
        float ov1 = __shfl_xor(v1b, o);
        float ov2 = __shfl_xor(v2b, o);
        int   oi1 = __shfl_xor(i1, o);
        int   oi2 = __shfl_xor(i2, o);
        if (ov1 > v1b || (ov1 == v1b && oi1 < i1)) {
            float nv2; int ni2;
            if (v1b > ov2 || (v1b == ov2 && i1 < oi2)) { nv2 = v1b; ni2 = i1; }
            else { nv2 = ov2; ni2 = oi2; }
            v1b = ov1; i1 = oi1; v2b = nv2; i2 = ni2;
        } else if (ov1 > v2b || (ov1 == v2b && oi1 < i2)) {
            v2b = ov1; i2 = oi1;
        }
    }
    if (lc == 0) {
        out_dpidx[row] = (float)i1;
        out_hnidx[row] = (float)i2;
        out_top1[row]  = v2b;
        ws_dpidx[row]  = i1;
        ws_hnidx[row]  = i2;
    }
}

// ---------------------------------------------------------------------------
// Kernel 3: all remaining outputs. grid = 2*B + K blocks:
//   [0, B)      : gather dp_centroid + hard_negative rows (float4/thread each)
//   [B, 2B)     : dp_cluster row i (16 floats/thread, int4 index loads)
//   [2B, 2B+K)  : index_dp row k (16 floats/thread)
// ---------------------------------------------------------------------------
__global__ __launch_bounds__(256) void kout_kernel(
    const float* __restrict__ cent,
    const int* __restrict__ dpidx, const int* __restrict__ hnidx,
    float* __restrict__ out_dpcent, float* __restrict__ out_hneg,
    float* __restrict__ out_cluster, float* __restrict__ out_indexdp)
{
    int bid = blockIdx.x;
    int tid = threadIdx.x;
    const int4* dpi4 = reinterpret_cast<const int4*>(dpidx);
    if (bid < B_N) {
        int b = bid;
        int i1 = dpidx[b], i2 = hnidx[b];
        float4 v1 = reinterpret_cast<const float4*>(cent + (size_t)i1 * D_N)[tid];
        float4 v2 = reinterpret_cast<const float4*>(cent + (size_t)i2 * D_N)[tid];
        reinterpret_cast<float4*>(out_dpcent + (size_t)b * D_N)[tid] = v1;
        reinterpret_cast<float4*>(out_hneg   + (size_t)b * D_N)[tid] = v2;
    } else if (bid < 2 * B_N) {
        int i = bid - B_N;
        int me = dpidx[i];
        float* dst = out_cluster + (size_t)i * B_N;
        #pragma unroll
        for (int q = 0; q < 4; ++q) {
            int j = tid * 16 + q * 4;
            int4 ix = dpi4[j >> 2];
            float4 v;
            v.x = (ix.x == me && (j + 0) != i) ? 1.0f : 0.0f;
            v.y = (ix.y == me && (j + 1) != i) ? 1.0f : 0.0f;
            v.z = (ix.z == me && (j + 2) != i) ? 1.0f : 0.0f;
            v.w = (ix.w == me && (j + 3) != i) ? 1.0f : 0.0f;
            *reinterpret_cast<float4*>(dst + j) = v;
        }
    } else {
        int k = bid - 2 * B_N;
        float* dst = out_indexdp + (size_t)k * B_N;
        #pragma unroll
        for (int q = 0; q < 4; ++q) {
            int j = tid * 16 + q * 4;
            int4 ix = dpi4[j >> 2];
            float4 v;
            v.x = (ix.x == k) ? 1.0f : 0.0f;
            v.y = (ix.y == k) ? 1.0f : 0.0f;
            v.z = (ix.z == k) ? 1.0f : 0.0f;
            v.w = (ix.w == k) ? 1.0f : 0.0f;
            *reinterpret_cast<float4*>(dst + j) = v;
        }
    }
}

extern "C" void kernel_launch(void* const* d_in, const int* in_sizes, int n_in,
                              void* d_out, int out_size, void* d_ws, size_t ws_size,
                              hipStream_t stream)
{
    const float* dp   = (const float*)d_in[0];   // 4096 x 1024 f32
    const float* cent = (const float*)d_in[1];   // 256 x 1024 f32
    // d_in[2] (batch_cos_sim) is unused by the reference outputs.
    float* out = (float*)d_out;

    // output layout (element offsets, all read back as f32)
    float* o_sims   = out;                 // 4096*256
    float* o_dpidx  = out + 1048576;       // 4096
    float* o_clust  = out + 1052672;       // 4096*4096
    float* o_idxdp  = out + 17829888;      // 256*4096
    float* o_dpcent = out + 18878464;      // 4096*1024
    float* o_hneg   = out + 23072768;      // 4096*1024
    float* o_hnidx  = out + 27267072;      // 4096
    float* o_top1   = out + 27271168;      // 4096

    char* ws = (char*)d_ws;
    ushort* dhi = (ushort*)ws;                          // 8 MiB
    ushort* dlo = (ushort*)(ws + (8u << 20));           // 8 MiB
    ushort* chi = (ushort*)(ws + (16u << 20));          // 512 KiB
    ushort* clo = (ushort*)(ws + (16u << 20) + (512u << 10));   // 512 KiB
    int*    widx = (int*)(ws + (17u << 20));            // 16 KiB
    int*    whn  = (int*)(ws + (17u << 20) + 16384);    // 16 KiB

    hipLaunchKernelGGL(knorm_kernel, dim3(K_N + B_N), dim3(256), 0, stream,
                       dp, cent, dhi, dlo, chi, clo);
    hipLaunchKernelGGL(kgemm_kernel, dim3(B_N / 16), dim3(256), 0, stream,
                       dhi, dlo, chi, clo, o_sims);
    hipLaunchKernelGGL(kreduce_kernel, dim3(B_N / 4), dim3(256), 0, stream,
                       o_sims, o_dpidx, o_hnidx, o_top1, widx, whn);
    hipLaunchKernelGGL(kout_kernel, dim3(2 * B_N + K_N), dim3(256), 0, stream,
                       cent, widx, whn, o_dpcent, o_hneg, o_clust, o_idxdp);
}

// Round 8
// 64.093 us; speedup vs baseline: 1.5758x; 1.4017x over previous
//
#include <hip/hip_runtime.h>
#include <hip/hip_bf16.h>
#include <math.h>

#define B_N 4096
#define D_N 1024
#define K_N 256
#define BK 32                 // k per LDS stage step
#define NSTEP (D_N / BK)      // 32

#define AS1 __attribute__((address_space(1)))
#define AS3 __attribute__((address_space(3)))

typedef __attribute__((ext_vector_type(8))) short bf16x8;   // 4 VGPR
typedef __attribute__((ext_vector_type(4))) float f32x4;    // MFMA C/D

static constexpr float K_EPS = 1e-8f;

static __device__ __forceinline__ unsigned short f32_to_bf16_rne(float f) {
    unsigned x = __builtin_bit_cast(unsigned, f);
    unsigned r = (x + 0x7FFFu + ((x >> 16) & 1u)) >> 16;
    return (unsigned short)r;
}
static __device__ __forceinline__ float bf16_bits_to_f32(unsigned short h) {
    unsigned x = ((unsigned)h) << 16;
    return __builtin_bit_cast(float, x);
}

// ---------------------------------------------------------------------------
// Kernel 1: normalize rows; emit bf16 hi/lo split of normalized vectors.
// ---------------------------------------------------------------------------
__global__ __launch_bounds__(256) void knorm_kernel(
    const float* __restrict__ dp, const float* __restrict__ cent,
    ushort* __restrict__ dhi, ushort* __restrict__ dlo,
    ushort* __restrict__ chi, ushort* __restrict__ clo)
{
    int bid = blockIdx.x;
    int tid = threadIdx.x;
    bool isC = bid < K_N;
    int row = isC ? bid : bid - K_N;
    const float* src = isC ? (cent + (size_t)row * D_N) : (dp + (size_t)row * D_N);
    float4 v = reinterpret_cast<const float4*>(src)[tid];
    float s = v.x * v.x + v.y * v.y + v.z * v.z + v.w * v.w;
    #pragma unroll
    for (int o = 32; o > 0; o >>= 1) s += __shfl_down(s, o);
    __shared__ float red[4];
    __shared__ float s_inv;
    if ((tid & 63) == 0) red[tid >> 6] = s;
    __syncthreads();
    if (tid == 0) {
        float t = red[0] + red[1] + red[2] + red[3];
        s_inv = 1.0f / fmaxf(sqrtf(t), K_EPS);
    }
    __syncthreads();
    float inv = s_inv;
    float e[4] = {v.x * inv, v.y * inv, v.z * inv, v.w * inv};
    ushort h4[4], l4[4];
    #pragma unroll
    for (int j = 0; j < 4; ++j) {
        ushort h = f32_to_bf16_rne(e[j]);
        float lo = e[j] - bf16_bits_to_f32(h);
        h4[j] = h;
        l4[j] = f32_to_bf16_rne(lo);
    }
    ushort* ph = (isC ? chi : dhi) + (size_t)row * D_N + tid * 4;
    ushort* pl = (isC ? clo : dlo) + (size_t)row * D_N + tid * 4;
    *reinterpret_cast<ushort4*>(ph) = make_ushort4(h4[0], h4[1], h4[2], h4[3]);
    *reinterpret_cast<ushort4*>(pl) = make_ushort4(l4[0], l4[1], l4[2], l4[3]);
}

// ---------------------------------------------------------------------------
// Kernel 2: sims = dn . cn^T via bf16 split-MFMA (3 products).
// grid = 256 blocks (1/CU) x 512 threads (8 waves, 2/SIMD).
// Per block: M=16 rows, N=256, K=1024 in 32 steps of BK=32.
// B (chi/clo) double-buffered in LDS (2 x 32KB), staged with global_load_lds
// BEFORE the MFMA cluster (T3-minimum: latency hides under compute, one
// barrier/step). XOR-swizzle both-sides: LDS slot (n,c) holds global chunk
// c^(n&3)  -> ds_read_b128 spreads 8 lanes per bank-quad (optimal).
// A-frags read per-lane from global (16 rows, L1-resident after warmup).
// Wave w owns n-tiles {2w, 2w+1}; 6 MFMA per step per wave.
// ---------------------------------------------------------------------------
__global__ __launch_bounds__(512) void kgemm_kernel(
    const ushort* __restrict__ dhi, const ushort* __restrict__ dlo,
    const ushort* __restrict__ chi, const ushort* __restrict__ clo,
    float* __restrict__ out_sims)
{
    __shared__ char ldsB[2][2][16384];   // [buf][hi/lo][16KB] = 64 KB
    int tid  = threadIdx.x;
    int lane = tid & 63;
    int w    = tid >> 6;                                   // wave 0..7
    int wu   = __builtin_amdgcn_readfirstlane(w);          // uniform for LDS dst
    int lr   = lane & 15;
    int lg   = lane >> 4;
    int brow = blockIdx.x * 16;

    // stage one 32KB B-slice (hi+lo) for k-range [k0, k0+32)
    auto stage = [&](int buf, int k0) {
        #pragma unroll
        for (int q = 0; q < 2; ++q) {
            int idx = wu * 2 + q;                 // 0..15, wave-uniform
            unsigned sl = (unsigned)(idx * 64 + lane);   // slot 0..1023
            unsigned n  = sl >> 2;                // centroid row 0..255
            unsigned c  = sl & 3;                 // 16B chunk within 64B row
            unsigned ko = (unsigned)k0 + ((c ^ (n & 3)) << 3);  // pre-swizzled src
            __builtin_amdgcn_global_load_lds(
                (const AS1 unsigned*)(chi + (size_t)n * D_N + ko),
                (AS3 unsigned*)(&ldsB[buf][0][0] + idx * 1024), 16, 0, 0);
            __builtin_amdgcn_global_load_lds(
                (const AS1 unsigned*)(clo + (size_t)n * D_N + ko),
                (AS3 unsigned*)(&ldsB[buf][1][0] + idx * 1024), 16, 0, 0);
        }
    };

    f32x4 acc[2] = {};

    stage(0, 0);
    __syncthreads();

    #pragma unroll 1
    for (int t = 0; t < NSTEP; ++t) {
        int cur = t & 1;
        int k0  = t * BK;
        if (t + 1 < NSTEP) stage(cur ^ 1, k0 + BK);   // issue-early

        // A-frags straight from global (L1-resident rows)
        size_t aoff = (size_t)(brow + lr) * D_N + k0 + lg * 8;
        bf16x8 ah = *reinterpret_cast<const bf16x8*>(&dhi[aoff]);
        bf16x8 al = *reinterpret_cast<const bf16x8*>(&dlo[aoff]);

        #pragma unroll
        for (int tt = 0; tt < 2; ++tt) {
            int n = (w * 2 + tt) * 16 + lr;
            unsigned boff = (unsigned)n * 64u + (unsigned)((lg ^ (n & 3)) << 4);
            bf16x8 bh = *reinterpret_cast<const bf16x8*>(&ldsB[cur][0][0] + boff);
            bf16x8 bl = *reinterpret_cast<const bf16x8*>(&ldsB[cur][1][0] + boff);
            acc[tt] = __builtin_amdgcn_mfma_f32_16x16x32_bf16(ah, bh, acc[tt], 0, 0, 0);
            acc[tt] = __builtin_amdgcn_mfma_f32_16x16x32_bf16(ah, bl, acc[tt], 0, 0, 0);
            acc[tt] = __builtin_amdgcn_mfma_f32_16x16x32_bf16(al, bh, acc[tt], 0, 0, 0);
        }
        __syncthreads();   // drains stage (vmcnt) + all reads of cur
    }

    // D layout: col = lane&15, row = (lane>>4)*4 + reg  (m89-verified)
    #pragma unroll
    for (int tt = 0; tt < 2; ++tt)
        #pragma unroll
        for (int r = 0; r < 4; ++r)
            out_sims[(size_t)(brow + lg * 4 + r) * K_N + (w * 2 + tt) * 16 + lr] =
                acc[tt][r];
}

// ---------------------------------------------------------------------------
// Kernel 2b: read sims, per-row top-2 (value + index) via butterfly merge.
// grid = 1024 blocks x 256 threads; wave per row.
// ---------------------------------------------------------------------------
__global__ __launch_bounds__(256) void kreduce_kernel(
    const float* __restrict__ sims,
    float* __restrict__ out_dpidx, float* __restrict__ out_hnidx,
    float* __restrict__ out_top1,
    int* __restrict__ ws_dpidx, int* __restrict__ ws_hnidx)
{
    int tid = threadIdx.x;
    int lc  = tid & 63;
    int row = blockIdx.x * 4 + (tid >> 6);

    float4 c = reinterpret_cast<const float4*>(sims)[(size_t)row * (K_N / 4) + lc];

    float v1b = c.x; int i1 = lc * 4;
    float v2b = -INFINITY; int i2 = 0;
    {
        float vals[3] = {c.y, c.z, c.w};
        #pragma unroll
        for (int j = 0; j < 3; ++j) {
            float val = vals[j]; int idx = lc * 4 + j + 1;
            if (val > v1b) { v2b = v1b; i2 = i1; v1b = val; i1 = idx; }
            else if (val > v2b) { v2b = val; i2 = idx; }
        }
    }
    #pragma unroll
    for (int o = 1; o < 64; o <<= 1) {
        float ov1 = __shfl_xor(v1b, o);
        float ov2 = __shfl_xor(v2b, o);
        int   oi1 = __shfl_xor(i1, o);
        int   oi2 = __shfl_xor(i2, o);
        if (ov1 > v1b || (ov1 == v1b && oi1 < i1)) {
            float nv2; int ni2;
            if (v1b > ov2 || (v1b == ov2 && i1 < oi2)) { nv2 = v1b; ni2 = i1; }
            else { nv2 = ov2; ni2 = oi2; }
            v1b = ov1; i1 = oi1; v2b = nv2; i2 = ni2;
        } else if (ov1 > v2b || (ov1 == v2b && oi1 < i2)) {
            v2b = ov1; i2 = oi1;
        }
    }
    if (lc == 0) {
        out_dpidx[row] = (float)i1;
        out_hnidx[row] = (float)i2;
        out_top1[row]  = v2b;
        ws_dpidx[row]  = i1;
        ws_hnidx[row]  = i2;
    }
}

// ---------------------------------------------------------------------------
// Kernel 3: all remaining outputs. grid = 2*B + K blocks; fully coalesced
// stores (thread q-th float4 at j = q*1024 + tid*4 -> 1KB/wave-instr).
// ---------------------------------------------------------------------------
__global__ __launch_bounds__(256) void kout_kernel(
    const float* __restrict__ cent,
    const int* __restrict__ dpidx, const int* __restrict__ hnidx,
    float* __restrict__ out_dpcent, float* __restrict__ out_hneg,
    float* __restrict__ out_cluster, float* __restrict__ out_indexdp)
{
    int bid = blockIdx.x;
    int tid = threadIdx.x;
    const int4* dpi4 = reinterpret_cast<const int4*>(dpidx);
    if (bid < B_N) {
        int b = bid;
        int i1 = dpidx[b], i2 = hnidx[b];
        float4 v1 = reinterpret_cast<const float4*>(cent + (size_t)i1 * D_N)[tid];
        float4 v2 = reinterpret_cast<const float4*>(cent + (size_t)i2 * D_N)[tid];
        reinterpret_cast<float4*>(out_dpcent + (size_t)b * D_N)[tid] = v1;
        reinterpret_cast<float4*>(out_hneg   + (size_t)b * D_N)[tid] = v2;
    } else if (bid < 2 * B_N) {
        int i = bid - B_N;
        int me = dpidx[i];
        float* dst = out_cluster + (size_t)i * B_N;
        #pragma unroll
        for (int q = 0; q < 4; ++q) {
            int j = q * 1024 + tid * 4;
            int4 ix = dpi4[j >> 2];
            float4 v;
            v.x = (ix.x == me && (j + 0) != i) ? 1.0f : 0.0f;
            v.y = (ix.y == me && (j + 1) != i) ? 1.0f : 0.0f;
            v.z = (ix.z == me && (j + 2) != i) ? 1.0f : 0.0f;
            v.w = (ix.w == me && (j + 3) != i) ? 1.0f : 0.0f;
            *reinterpret_cast<float4*>(dst + j) = v;
        }
    } else {
        int k = bid - 2 * B_N;
        float* dst = out_indexdp + (size_t)k * B_N;
        #pragma unroll
        for (int q = 0; q < 4; ++q) {
            int j = q * 1024 + tid * 4;
            int4 ix = dpi4[j >> 2];
            float4 v;
            v.x = (ix.x == k) ? 1.0f : 0.0f;
            v.y = (ix.y == k) ? 1.0f : 0.0f;
            v.z = (ix.z == k) ? 1.0f : 0.0f;
            v.w = (ix.w == k) ? 1.0f : 0.0f;
            *reinterpret_cast<float4*>(dst + j) = v;
        }
    }
}

extern "C" void kernel_launch(void* const* d_in, const int* in_sizes, int n_in,
                              void* d_out, int out_size, void* d_ws, size_t ws_size,
                              hipStream_t stream)
{
    const float* dp   = (const float*)d_in[0];   // 4096 x 1024 f32
    const float* cent = (const float*)d_in[1];   // 256 x 1024 f32
    // d_in[2] (batch_cos_sim) is unused by the reference outputs.
    float* out = (float*)d_out;

    float* o_sims   = out;                 // 4096*256
    float* o_dpidx  = out + 1048576;       // 4096
    float* o_clust  = out + 1052672;       // 4096*4096
    float* o_idxdp  = out + 17829888;      // 256*4096
    float* o_dpcent = out + 18878464;      // 4096*1024
    float* o_hneg   = out + 23072768;      // 4096*1024
    float* o_hnidx  = out + 27267072;      // 4096
    float* o_top1   = out + 27271168;      // 4096

    char* ws = (char*)d_ws;
    ushort* dhi = (ushort*)ws;                          // 8 MiB
    ushort* dlo = (ushort*)(ws + (8u << 20));           // 8 MiB
    ushort* chi = (ushort*)(ws + (16u << 20));          // 512 KiB
    ushort* clo = (ushort*)(ws + (16u << 20) + (512u << 10));   // 512 KiB
    int*    widx = (int*)(ws + (17u << 20));            // 16 KiB
    int*    whn  = (int*)(ws + (17u << 20) + 16384);    // 16 KiB

    hipLaunchKernelGGL(knorm_kernel, dim3(K_N + B_N), dim3(256), 0, stream,
                       dp, cent, dhi, dlo, chi, clo);
    hipLaunchKernelGGL(kgemm_kernel, dim3(B_N / 16), dim3(512), 0, stream,
                       dhi, dlo, chi, clo, o_sims);
    hipLaunchKernelGGL(kreduce_kernel, dim3(B_N / 4), dim3(256), 0, stream,
                       o_sims, o_dpidx, o_hnidx, o_top1, widx, whn);
    hipLaunchKernelGGL(kout_kernel, dim3(2 * B_N + K_N), dim3(256), 0, stream,
                       cent, widx, whn, o_dpcent, o_hneg, o_clust, o_idxdp);
}